// Round 14
// baseline (702.459 us; speedup 1.0000x reference)
//
#include <hip/hip_runtime.h>
#include <cstdint>
#include <cstddef>

// GRU (reset_after) + dense(1)+sigmoid, masked by per-batch length t.
// R14: TWO sequences per wave (256 blocks x 64 threads), zero barriers.
// A tiny rank-sort pre-kernel pairs sequences by length (block k gets
// ranks 2k,2k+1 => tA >= tB) so the critical block runs dual to the end.
// The dual step is MANUALLY FUSED: all LDS reads first (xA,xB,hA,hB),
// then interleaved A/B gate chains -- B's issue fills A's latency (R12/R13
// showed the single-seq step has ~550cy exposed latency, only ~340cy issue).
// Weights are SHARED between the two sequences (same 132 f16-pair VGPRs).
// Per-seq: lane j owns gate cols {j,64+j,128+j} full-K via v_dot2_f32_f16,
// h state f16 in LDS (same-wave write->read), z/r weights pre-negated,
// c weights pre-doubled (R6/R11-proven folds).

typedef float  v2f __attribute__((ext_vector_type(2)));
typedef float  v4f __attribute__((ext_vector_type(4)));
typedef _Float16 h2 __attribute__((ext_vector_type(2)));
typedef _Float16 h8 __attribute__((ext_vector_type(8)));

__device__ __forceinline__ float frcp(float x) { return __builtin_amdgcn_rcpf(x); }

#if defined(__has_builtin)
#if __has_builtin(__builtin_amdgcn_fdot2)
#define HAVE_FDOT2 1
#endif
#endif

__device__ __forceinline__ float fdot2(h2 a, h2 b, float acc) {
#ifdef HAVE_FDOT2
    return __builtin_amdgcn_fdot2(a, b, acc, false);
#else
    return fmaf((float)a.x, (float)b.x, fmaf((float)a.y, (float)b.y, acc));
#endif
}

#define PAIR(v8, m) __builtin_shufflevector((v8), (v8), 2*(m), 2*(m)+1)

#define DOT4(acc, Warr, off, v)                              \
    acc = fdot2((Warr)[(off) + 0], PAIR((v), 0), acc);       \
    acc = fdot2((Warr)[(off) + 1], PAIR((v), 1), acc);       \
    acc = fdot2((Warr)[(off) + 2], PAIR((v), 2), acc);       \
    acc = fdot2((Warr)[(off) + 3], PAIR((v), 3), acc);

// ---------- rank-sort pre-kernel: perm[rank] = seq index, rank 0 = longest ----------
__global__ void rank512_kernel(const int* __restrict__ tg, int* __restrict__ perm) {
    const int i = threadIdx.x;          // 0..511
    const int ti = tg[i];
    int rank = 0;
    for (int k = 0; k < 512; ++k) {
        const int tk = tg[k];
        rank += (int)((tk > ti) | ((tk == ti) & (k < i)));
    }
    perm[rank] = i;
}

// ---------- staging helpers (24 f32 -> 24 f16 row) ----------
#define STAGE24(DSTP, SRCP)                                                     \
  { const v4f* s_ = (const v4f*)(SRCP);                                         \
    const v4f g0_=s_[0],g1_=s_[1],g2_=s_[2],g3_=s_[3],g4_=s_[4],g5_=s_[5];      \
    h8 o0_,o1_,o2_;                                                             \
    _Pragma("unroll")                                                           \
    for (int i_=0;i_<4;++i_){ o0_[i_]=(_Float16)g0_[i_]; o0_[4+i_]=(_Float16)g1_[i_]; \
      o1_[i_]=(_Float16)g2_[i_]; o1_[4+i_]=(_Float16)g3_[i_];                   \
      o2_[i_]=(_Float16)g4_[i_]; o2_[4+i_]=(_Float16)g5_[i_]; }                 \
    h8* d_=(h8*)(DSTP); d_[0]=o0_; d_[1]=o1_; d_[2]=o2_; }

#define PREFETCH24(PF, SRCP)                                                    \
  { const v4f* s_=(const v4f*)(SRCP);                                           \
    _Pragma("unroll") for (int i_=0;i_<6;++i_) (PF)[i_]=s_[i_]; }

#define COMMIT24(DSTP, PF)                                                      \
  { h8 o0_,o1_,o2_;                                                             \
    _Pragma("unroll")                                                           \
    for (int i_=0;i_<4;++i_){ o0_[i_]=(_Float16)(PF)[0][i_]; o0_[4+i_]=(_Float16)(PF)[1][i_]; \
      o1_[i_]=(_Float16)(PF)[2][i_]; o1_[4+i_]=(_Float16)(PF)[3][i_];           \
      o2_[i_]=(_Float16)(PF)[4][i_]; o2_[4+i_]=(_Float16)(PF)[5][i_]; }         \
    h8* d_=(h8*)(DSTP); d_[0]=o0_; d_[1]=o1_; d_[2]=o2_; }

// ---------- per-chunk output reduce (row j of p_lds[S]) ----------
#define REDUCE_CHUNK(S, RBASE, RCNT, TI, OUTB)                                  \
  if (j < (RCNT)) {                                                             \
    const v2f* pr_ = (const v2f*)(&p_lds[S][j*66]);                             \
    v2f a2_ = (v2f){0.f,0.f};                                                   \
    _Pragma("unroll") for (int i_=0;i_<32;++i_) a2_ += pr_[i_];                 \
    const float o_ = frcp(1.f + __expf(-(a2_.x + a2_.y + bdv)));                \
    (OUTB)[(RBASE)+j] = o_;                                                     \
    if ((RBASE)+j == (TI)-1) olast[S] = o_;                                     \
  }

// ---------- single-sequence step (R12-proven body, seq 0) ----------
#define STEP_A(C)                                                               \
  { const h8* xp_ = (const h8*)(&xbuf[0][(C)*24]);                              \
    const h8 xa_=xp_[0], xb_=xp_[1], xc_=xp_[2];                                \
    const h8* hp_ = (const h8*)(&h16[0][0]);                                    \
    const h8 h0_=hp_[0],h1_=hp_[1],h2_=hp_[2],h3_=hp_[3],                       \
             h4_=hp_[4],h5_=hp_[5],h6_=hp_[6],h7_=hp_[7];                       \
    float ran_=brn, zan_=bzn, xca_=b0c2;                                        \
    DOT4(ran_,Wr,0,xa_); DOT4(ran_,Wr,4,xb_); DOT4(ran_,Wr,8,xc_);              \
    DOT4(zan_,Wz,0,xa_); DOT4(zan_,Wz,4,xb_); DOT4(zan_,Wz,8,xc_);              \
    DOT4(xca_,Wc,0,xa_); DOT4(xca_,Wc,4,xb_); DOT4(xca_,Wc,8,xc_);              \
    DOT4(ran_,Ur,0,h0_); DOT4(ran_,Ur,4,h1_); DOT4(ran_,Ur,8,h2_);              \
    DOT4(ran_,Ur,12,h3_); DOT4(ran_,Ur,16,h4_); DOT4(ran_,Ur,20,h5_);           \
    DOT4(ran_,Ur,24,h6_); DOT4(ran_,Ur,28,h7_);                                 \
    const float er_ = __expf(ran_);                                             \
    DOT4(zan_,Uz,0,h0_); DOT4(zan_,Uz,4,h1_); DOT4(zan_,Uz,8,h2_);              \
    DOT4(zan_,Uz,12,h3_); DOT4(zan_,Uz,16,h4_); DOT4(zan_,Uz,20,h5_);           \
    DOT4(zan_,Uz,24,h6_); DOT4(zan_,Uz,28,h7_);                                 \
    const float ez_ = __expf(zan_);                                             \
    float ca_ = b1c2;                                                           \
    DOT4(ca_,Uc,0,h0_); DOT4(ca_,Uc,4,h1_); DOT4(ca_,Uc,8,h2_);                 \
    DOT4(ca_,Uc,12,h3_); DOT4(ca_,Uc,16,h4_); DOT4(ca_,Uc,20,h5_);              \
    DOT4(ca_,Uc,24,h6_); DOT4(ca_,Uc,28,h7_);                                   \
    const float r_ = frcp(1.f + er_);                                           \
    const float z_ = frcp(1.f + ez_);                                           \
    const float y_ = fmaf(r_, ca_, xca_);                                       \
    const float cg_ = 1.f - 2.f * frcp(1.f + __expf(y_));                       \
    const float hn_ = fmaf(z_, holdA - cg_, cg_);                               \
    holdA = hn_;                                                                \
    h16[0][j] = (_Float16)hn_;                                                  \
    p_lds[0][(C)*66+j] = hn_ * wdj;                                             \
  }

// ---------- fused dual step: reads first, interleaved A/B chains ----------
#define DUAL_STEP(C)                                                            \
  { const h8* xpA_ = (const h8*)(&xbuf[0][(C)*24]);                             \
    const h8 xaA_=xpA_[0], xbA_=xpA_[1], xcA_=xpA_[2];                          \
    const h8* xpB_ = (const h8*)(&xbuf[1][(C)*24]);                             \
    const h8 xaB_=xpB_[0], xbB_=xpB_[1], xcB_=xpB_[2];                          \
    const h8* hpA_ = (const h8*)(&h16[0][0]);                                   \
    const h8 hA0_=hpA_[0],hA1_=hpA_[1],hA2_=hpA_[2],hA3_=hpA_[3],               \
             hA4_=hpA_[4],hA5_=hpA_[5],hA6_=hpA_[6],hA7_=hpA_[7];               \
    const h8* hpB_ = (const h8*)(&h16[1][0]);                                   \
    const h8 hB0_=hpB_[0],hB1_=hpB_[1],hB2_=hpB_[2],hB3_=hpB_[3],               \
             hB4_=hpB_[4],hB5_=hpB_[5],hB6_=hpB_[6],hB7_=hpB_[7];               \
    float ranA_=brn, zanA_=bzn, xcaA_=b0c2;                                     \
    float ranB_=brn, zanB_=bzn, xcaB_=b0c2;                                     \
    DOT4(ranA_,Wr,0,xaA_); DOT4(ranA_,Wr,4,xbA_); DOT4(ranA_,Wr,8,xcA_);        \
    DOT4(ranB_,Wr,0,xaB_); DOT4(ranB_,Wr,4,xbB_); DOT4(ranB_,Wr,8,xcB_);        \
    DOT4(zanA_,Wz,0,xaA_); DOT4(zanA_,Wz,4,xbA_); DOT4(zanA_,Wz,8,xcA_);        \
    DOT4(zanB_,Wz,0,xaB_); DOT4(zanB_,Wz,4,xbB_); DOT4(zanB_,Wz,8,xcB_);        \
    DOT4(xcaA_,Wc,0,xaA_); DOT4(xcaA_,Wc,4,xbA_); DOT4(xcaA_,Wc,8,xcA_);        \
    DOT4(xcaB_,Wc,0,xaB_); DOT4(xcaB_,Wc,4,xbB_); DOT4(xcaB_,Wc,8,xcB_);        \
    DOT4(ranA_,Ur,0,hA0_); DOT4(ranA_,Ur,4,hA1_); DOT4(ranA_,Ur,8,hA2_);        \
    DOT4(ranA_,Ur,12,hA3_); DOT4(ranA_,Ur,16,hA4_); DOT4(ranA_,Ur,20,hA5_);     \
    DOT4(ranA_,Ur,24,hA6_); DOT4(ranA_,Ur,28,hA7_);                             \
    const float erA_ = __expf(ranA_);                                           \
    DOT4(ranB_,Ur,0,hB0_); DOT4(ranB_,Ur,4,hB1_); DOT4(ranB_,Ur,8,hB2_);        \
    DOT4(ranB_,Ur,12,hB3_); DOT4(ranB_,Ur,16,hB4_); DOT4(ranB_,Ur,20,hB5_);     \
    DOT4(ranB_,Ur,24,hB6_); DOT4(ranB_,Ur,28,hB7_);                             \
    const float erB_ = __expf(ranB_);                                           \
    DOT4(zanA_,Uz,0,hA0_); DOT4(zanA_,Uz,4,hA1_); DOT4(zanA_,Uz,8,hA2_);        \
    DOT4(zanA_,Uz,12,hA3_); DOT4(zanA_,Uz,16,hA4_); DOT4(zanA_,Uz,20,hA5_);     \
    DOT4(zanA_,Uz,24,hA6_); DOT4(zanA_,Uz,28,hA7_);                             \
    const float ezA_ = __expf(zanA_);                                           \
    DOT4(zanB_,Uz,0,hB0_); DOT4(zanB_,Uz,4,hB1_); DOT4(zanB_,Uz,8,hB2_);        \
    DOT4(zanB_,Uz,12,hB3_); DOT4(zanB_,Uz,16,hB4_); DOT4(zanB_,Uz,20,hB5_);     \
    DOT4(zanB_,Uz,24,hB6_); DOT4(zanB_,Uz,28,hB7_);                             \
    const float ezB_ = __expf(zanB_);                                           \
    float caA_ = b1c2;                                                          \
    DOT4(caA_,Uc,0,hA0_); DOT4(caA_,Uc,4,hA1_); DOT4(caA_,Uc,8,hA2_);           \
    DOT4(caA_,Uc,12,hA3_); DOT4(caA_,Uc,16,hA4_); DOT4(caA_,Uc,20,hA5_);        \
    DOT4(caA_,Uc,24,hA6_); DOT4(caA_,Uc,28,hA7_);                               \
    float caB_ = b1c2;                                                          \
    DOT4(caB_,Uc,0,hB0_); DOT4(caB_,Uc,4,hB1_); DOT4(caB_,Uc,8,hB2_);           \
    DOT4(caB_,Uc,12,hB3_); DOT4(caB_,Uc,16,hB4_); DOT4(caB_,Uc,20,hB5_);        \
    DOT4(caB_,Uc,24,hB6_); DOT4(caB_,Uc,28,hB7_);                               \
    const float rA_ = frcp(1.f + erA_), zA_ = frcp(1.f + ezA_);                 \
    const float rB_ = frcp(1.f + erB_), zB_ = frcp(1.f + ezB_);                 \
    const float yA_ = fmaf(rA_, caA_, xcaA_);                                   \
    const float yB_ = fmaf(rB_, caB_, xcaB_);                                   \
    const float cgA_ = 1.f - 2.f * frcp(1.f + __expf(yA_));                     \
    const float cgB_ = 1.f - 2.f * frcp(1.f + __expf(yB_));                     \
    const float hnA_ = fmaf(zA_, holdA - cgA_, cgA_);                           \
    const float hnB_ = fmaf(zB_, holdB - cgB_, cgB_);                           \
    holdA = hnA_;  holdB = hnB_;                                                \
    h16[0][j] = (_Float16)hnA_;  h16[1][j] = (_Float16)hnB_;                    \
    p_lds[0][(C)*66+j] = hnA_ * wdj;  p_lds[1][(C)*66+j] = hnB_ * wdj;          \
  }

__global__ __launch_bounds__(64, 1) void gru_dual_kernel(
    const float* __restrict__ xg,      // (512,1024,24)
    const int*   __restrict__ tg,      // (512,)
    const float* __restrict__ Wg,      // (24,192)
    const float* __restrict__ Ug,      // (64,192)
    const float* __restrict__ bg,      // (2,192)
    const float* __restrict__ Wdg,     // (64,1)
    const float* __restrict__ bdg,     // (1,)
    const int*   __restrict__ perm,    // (512,) rank -> seq
    float*       __restrict__ outg)    // (512,1024)
{
    const int b = blockIdx.x;           // 0..255
    const int j = threadIdx.x;          // lane 0..63

    __shared__ __align__(16) _Float16 h16[2][64];
    __shared__ __align__(16) _Float16 xbuf[2][64 * 24];
    __shared__ __align__(16) float    p_lds[2][64 * 66];
    __shared__ float olast[2];

    const int sA = perm[2 * b];
    const int sB = perm[2 * b + 1];
    const int tA = tg[sA];
    const int tB = tg[sB];              // tA >= tB by rank order
    float* outA = outg + (size_t)sA * 1024;
    float* outB = outg + (size_t)sB * 1024;
    const float bdv = bdg[0];
    const float sbd = frcp(1.f + __expf(-bdv));

    if (tA <= 0) {                      // both zero-length
        for (int i = j; i < 1024; i += 64) { outA[i] = sbd; outB[i] = sbd; }
        return;
    }

    // ---- shared weight preload: f16 pairs along K; z/r negated, c doubled ----
    h2 Uz[32], Ur[32], Uc[32];
    #pragma unroll
    for (int k = 0; k < 32; ++k) {
        const float* r0 = Ug + (2 * k)     * 192;
        const float* r1 = Ug + (2 * k + 1) * 192;
        Uz[k] = (h2){ (_Float16)(-r0[j]),            (_Float16)(-r1[j]) };
        Ur[k] = (h2){ (_Float16)(-r0[64 + j]),       (_Float16)(-r1[64 + j]) };
        Uc[k] = (h2){ (_Float16)(2.f * r0[128 + j]), (_Float16)(2.f * r1[128 + j]) };
    }
    h2 Wz[12], Wr[12], Wc[12];
    #pragma unroll
    for (int d = 0; d < 12; ++d) {
        const float* r0 = Wg + (2 * d)     * 192;
        const float* r1 = Wg + (2 * d + 1) * 192;
        Wz[d] = (h2){ (_Float16)(-r0[j]),            (_Float16)(-r1[j]) };
        Wr[d] = (h2){ (_Float16)(-r0[64 + j]),       (_Float16)(-r1[64 + j]) };
        Wc[d] = (h2){ (_Float16)(2.f * r0[128 + j]), (_Float16)(2.f * r1[128 + j]) };
    }
    const float bzn  = -(bg[j]      + bg[192 + j]);
    const float brn  = -(bg[64 + j] + bg[256 + j]);
    const float b0c2 = 2.f * bg[128 + j];
    const float b1c2 = 2.f * bg[320 + j];
    const float wdj  = Wdg[j];

    const float* xbA = xg + (size_t)sA * 24576;
    const float* xbB = xg + (size_t)sB * 24576;

    // ---- stage chunk 0; init h; prefetch chunk 1 ----
    STAGE24(&xbuf[0][j * 24], xbA + j * 24);
    if (tB > 0) STAGE24(&xbuf[1][j * 24], xbB + j * 24);
    h16[0][j] = (_Float16)0.f;
    h16[1][j] = (_Float16)0.f;

    v4f pfA[6], pfB[6];
    if (tA > 64) PREFETCH24(pfA, xbA + 1536 + j * 24);
    if (tB > 64) PREFETCH24(pfB, xbB + 1536 + j * 24);

    float holdA = 0.f, holdB = 0.f;

    for (int base = 0; base < tA; base += 64) {
        const int  cnt  = (tA - base < 64) ? (tA - base) : 64;
        const bool dual = base < tB;

        if (base > 0) {
            const int rbase = base - 64;
            REDUCE_CHUNK(0, rbase, 64, tA, outA);
            if (rbase < tB) { REDUCE_CHUNK(1, rbase, 64, tB, outB); }
            COMMIT24(&xbuf[0][j * 24], pfA);
            if (dual) COMMIT24(&xbuf[1][j * 24], pfB);
            if (base + 64 < tA) PREFETCH24(pfA, xbA + (size_t)(base + 64) * 24 + j * 24);
            if (base + 64 < tB) PREFETCH24(pfB, xbB + (size_t)(base + 64) * 24 + j * 24);
        }

        if (dual) {
            for (int c = 0; c < cnt; ++c) { DUAL_STEP(c); }
        } else {
            for (int c = 0; c < cnt; ++c) { STEP_A(c); }
        }
    }

    // ---- final chunk reduce ----
    const int lastbase = ((tA - 1) >> 6) << 6;
    const int lastcnt  = tA - lastbase;
    REDUCE_CHUNK(0, lastbase, lastcnt, tA, outA);
    if (lastbase < tB) { REDUCE_CHUNK(1, lastbase, lastcnt, tB, outB); }

    // ---- constant tail fills (h frozen for s >= t_i) ----
    const float fillA = olast[0];
    const float fillB = (tB > 0) ? olast[1] : sbd;
    for (int i = tA + j; i < 1024; i += 64) outA[i] = fillA;
    for (int i = tB + j; i < 1024; i += 64) outB[i] = fillB;
}

extern "C" void kernel_launch(void* const* d_in, const int* in_sizes, int n_in,
                              void* d_out, int out_size, void* d_ws, size_t ws_size,
                              hipStream_t stream) {
    (void)in_sizes; (void)n_in; (void)ws_size; (void)out_size;
    const float* x  = (const float*)d_in[0];
    const int*   t  = (const int*)d_in[1];
    const float* W  = (const float*)d_in[2];
    const float* U  = (const float*)d_in[3];
    const float* bb = (const float*)d_in[4];
    const float* Wd = (const float*)d_in[5];
    const float* bd = (const float*)d_in[6];
    float* out = (float*)d_out;
    int*   perm = (int*)d_ws;           // 512 ints, rewritten every call

    hipLaunchKernelGGL(rank512_kernel, dim3(1), dim3(512), 0, stream, t, perm);
    hipLaunchKernelGGL(gru_dual_kernel, dim3(256), dim3(64), 0, stream,
                       x, t, W, U, bb, Wd, bd, perm, out);
}

// Round 15
// 379.325 us; speedup vs baseline: 1.8519x; 1.8519x over previous
//
#include <hip/hip_runtime.h>
#include <cstdint>
#include <cstddef>

// GRU (reset_after) + dense(1)+sigmoid, masked by per-batch length t.
// R15 = R12 with the gate dot-chains INTERLEAVED at instruction granularity.
// Key insight (finally consistent with R12-neutral/R13-worse/R14-worse):
// CDNA issue is IN-ORDER per wave. R12's three gate chains (44 serial
// dependent dot2s each, ~5cy dep latency) could not overlap -- a stalled
// dot blocks all later instructions -- so the step paid ~3x220cy of chain
// serialization. Emitting r,z,c dots ALTERNATELY puts each accumulator's
// reuse 3 instructions (~6cy) away -> stall-free issue: 96 U-dots in
// ~192cy + 36 W-dots in ~72cy. W/U accumulators are separate (merged at
// the end) so the W chain doesn't extend the U chain.
// Structure unchanged from R12: ONE WAVE per sequence (512 x 64), ZERO
// barriers, lane j owns gate cols {j,64+j,128+j} full-K, f16-pair weights
// in VGPRs via v_dot2_f32_f16, h state f16 in LDS (same-wave write->read),
// z/r weights pre-negated, c weights pre-doubled.

typedef float  v2f __attribute__((ext_vector_type(2)));
typedef float  v4f __attribute__((ext_vector_type(4)));
typedef _Float16 h2 __attribute__((ext_vector_type(2)));
typedef _Float16 h8 __attribute__((ext_vector_type(8)));

__device__ __forceinline__ float frcp(float x) { return __builtin_amdgcn_rcpf(x); }

#if defined(__has_builtin)
#if __has_builtin(__builtin_amdgcn_fdot2)
#define HAVE_FDOT2 1
#endif
#endif

__device__ __forceinline__ float fdot2(h2 a, h2 b, float acc) {
#ifdef HAVE_FDOT2
    return __builtin_amdgcn_fdot2(a, b, acc, false);
#else
    return fmaf((float)a.x, (float)b.x, fmaf((float)a.y, (float)b.y, acc));
#endif
}

#define PAIR(v8, m) __builtin_shufflevector((v8), (v8), 2*(m), 2*(m)+1)

// one interleaved r/z/c trio for pair m of vector v (U-part)
#define UTRIO(off, v, m)                                     \
    ru = fdot2(Ur[(off)+(m)], PAIR((v),(m)), ru);            \
    zu = fdot2(Uz[(off)+(m)], PAIR((v),(m)), zu);            \
    cu = fdot2(Uc[(off)+(m)], PAIR((v),(m)), cu);
#define UTRIO4(off, v) UTRIO(off, v, 0) UTRIO(off, v, 1) UTRIO(off, v, 2) UTRIO(off, v, 3)

// one interleaved r/z/c trio for pair m of vector v (W-part)
#define WTRIO(off, v, m)                                     \
    rw = fdot2(Wr[(off)+(m)], PAIR((v),(m)), rw);            \
    zw = fdot2(Wz[(off)+(m)], PAIR((v),(m)), zw);            \
    cw = fdot2(Wc[(off)+(m)], PAIR((v),(m)), cw);
#define WTRIO4(off, v) WTRIO(off, v, 0) WTRIO(off, v, 1) WTRIO(off, v, 2) WTRIO(off, v, 3)

__global__ __launch_bounds__(64, 1) void gru1_kernel(
    const float* __restrict__ xg,      // (512,1024,24)
    const int*   __restrict__ tg,      // (512,)
    const float* __restrict__ Wg,      // (24,192)
    const float* __restrict__ Ug,      // (64,192)
    const float* __restrict__ bg,      // (2,192)
    const float* __restrict__ Wdg,     // (64,1)
    const float* __restrict__ bdg,     // (1,)
    float*       __restrict__ outg)    // (512,1024)
{
    const int b = blockIdx.x;
    const int j = threadIdx.x;          // lane 0..63

    __shared__ __align__(16) _Float16 h16[64];          // f16 state, 128 B
    __shared__ __align__(16) _Float16 xbuf[64 * 24];    // chunk of x, f16
    __shared__ __align__(16) float    p_lds[64 * 66];   // [step][lane], pad 66
    __shared__ float o_last;

    const int   t    = tg[b];
    float*      outb = outg + (size_t)b * 1024;
    const float bdv  = bdg[0];

    if (t <= 0) {
        const float fill = frcp(1.f + __expf(-bdv));
        for (int i = j; i < 1024; i += 64) outb[i] = fill;
        return;
    }

    // ---- weight preload: f16 pairs along K; z/r negated, c doubled ----
    h2 Uz[32], Ur[32], Uc[32];
    #pragma unroll
    for (int k = 0; k < 32; ++k) {
        const float* r0 = Ug + (2 * k)     * 192;
        const float* r1 = Ug + (2 * k + 1) * 192;
        Uz[k] = (h2){ (_Float16)(-r0[j]),            (_Float16)(-r1[j]) };
        Ur[k] = (h2){ (_Float16)(-r0[64 + j]),       (_Float16)(-r1[64 + j]) };
        Uc[k] = (h2){ (_Float16)(2.f * r0[128 + j]), (_Float16)(2.f * r1[128 + j]) };
    }
    h2 Wz[12], Wr[12], Wc[12];
    #pragma unroll
    for (int d = 0; d < 12; ++d) {
        const float* r0 = Wg + (2 * d)     * 192;
        const float* r1 = Wg + (2 * d + 1) * 192;
        Wz[d] = (h2){ (_Float16)(-r0[j]),            (_Float16)(-r1[j]) };
        Wr[d] = (h2){ (_Float16)(-r0[64 + j]),       (_Float16)(-r1[64 + j]) };
        Wc[d] = (h2){ (_Float16)(2.f * r0[128 + j]), (_Float16)(2.f * r1[128 + j]) };
    }
    const float bzn  = -(bg[j]      + bg[192 + j]);     // z: negated
    const float brn  = -(bg[64 + j] + bg[256 + j]);     // r: negated
    const float b0c2 = 2.f * bg[128 + j];               // c: doubled
    const float b1c2 = 2.f * bg[320 + j];
    const float wdj  = Wdg[j];

    const float* xb = xg + (size_t)b * 24576;   // 1024*24

    // ---- stage chunk 0: lane j handles x row j (24 f32 -> 24 f16) ----
    {
        const v4f* src = (const v4f*)(xb + j * 24);
        v4f g0 = src[0], g1 = src[1], g2 = src[2], g3 = src[3], g4 = src[4], g5 = src[5];
        h8 o0, o1, o2;
        #pragma unroll
        for (int i = 0; i < 4; ++i) {
            o0[i]     = (_Float16)g0[i];  o0[4 + i] = (_Float16)g1[i];
            o1[i]     = (_Float16)g2[i];  o1[4 + i] = (_Float16)g3[i];
            o2[i]     = (_Float16)g4[i];  o2[4 + i] = (_Float16)g5[i];
        }
        h8* dst = (h8*)(xbuf + j * 24);
        dst[0] = o0; dst[1] = o1; dst[2] = o2;
    }
    h16[j] = (_Float16)0.f;

    // prefetch chunk 1 (f32, converted at commit)
    v4f pf[6];
    if (t > 64) {
        const v4f* ns = (const v4f*)(xb + 1536 + j * 24);
        #pragma unroll
        for (int i = 0; i < 6; ++i) pf[i] = ns[i];
    }

    float hold = 0.f;   // lane j's own h_j (f32, full precision)

    for (int base = 0; base < t; base += 64) {
        const int cnt = (t - base < 64) ? (t - base) : 64;

        if (base > 0) {
            // previous chunk done. Reduce its outputs (before p_lds reuse),
            // commit prefetched x, prefetch next. Same-wave ordering only.
            {
                const v2f* pr = (const v2f*)(p_lds + j * 66);
                v2f s2 = (v2f){0.f, 0.f};
                #pragma unroll
                for (int i = 0; i < 32; ++i) s2 += pr[i];
                outb[base - 64 + j] = frcp(1.f + __expf(-(s2.x + s2.y + bdv)));
            }
            {
                h8 o0, o1, o2;
                #pragma unroll
                for (int i = 0; i < 4; ++i) {
                    o0[i]     = (_Float16)pf[0][i];  o0[4 + i] = (_Float16)pf[1][i];
                    o1[i]     = (_Float16)pf[2][i];  o1[4 + i] = (_Float16)pf[3][i];
                    o2[i]     = (_Float16)pf[4][i];  o2[4 + i] = (_Float16)pf[5][i];
                }
                h8* dst = (h8*)(xbuf + j * 24);
                dst[0] = o0; dst[1] = o1; dst[2] = o2;
            }
            if (base + 64 < t) {
                const v4f* ns = (const v4f*)(xb + (size_t)(base + 64) * 24 + j * 24);
                #pragma unroll
                for (int i = 0; i < 6; ++i) pf[i] = ns[i];
            }
        }

        for (int c = 0; c < cnt; ++c) {
            // ---- issue x reads first (needed by the W block), then h ----
            const h8* xp = (const h8*)(xbuf + c * 24);
            h8 xa = xp[0], xcv = xp[1], xe = xp[2];
            const h8* hp = (const h8*)h16;
            h8 hv[8];
            #pragma unroll
            for (int i = 0; i < 8; ++i) hv[i] = hp[i];

            // ---- W block: 36 dots, r/z/c interleaved, separate accs ----
            float rw = brn, zw = bzn, cw = b0c2;
            WTRIO4(0, xa) WTRIO4(4, xcv) WTRIO4(8, xe)

            // ---- U block: 96 dots, r/z/c interleaved (dep distance 3
            //      instrs ~6cy > ~5cy dot latency -> stall-free issue) ----
            float ru = 0.f, zu = 0.f, cu = b1c2;
            UTRIO4( 0, hv[0]) UTRIO4( 4, hv[1]) UTRIO4( 8, hv[2])
            UTRIO4(12, hv[3]) UTRIO4(16, hv[4]) UTRIO4(20, hv[5])
            UTRIO4(24, hv[6]) UTRIO4(28, hv[7])

            // ---- merge + gates ----
            const float er = __expf(rw + ru);
            const float ez = __expf(zw + zu);
            const float r  = frcp(1.f + er);
            const float z  = frcp(1.f + ez);
            const float y  = fmaf(r, cu, cw);                  // 2*(xc + r*hc)
            const float cg = 1.f - 2.f * frcp(1.f + __expf(y));
            const float hn = fmaf(z, hold - cg, cg);           // z*h + (1-z)*c
            hold = hn;

            h16[j] = (_Float16)hn;          // next step's state (ds_write_b16)
            p_lds[c * 66 + j] = hn * wdj;   // output partial
        }
    }

    // ---- final (possibly partial) chunk reduce ----
    const int lastbase = ((t - 1) >> 6) << 6;
    const int lastcnt  = t - lastbase;
    if (j < lastcnt) {
        const v2f* pr = (const v2f*)(p_lds + j * 66);
        v2f s2 = (v2f){0.f, 0.f};
        #pragma unroll
        for (int i = 0; i < 32; ++i) s2 += pr[i];
        const float o = frcp(1.f + __expf(-(s2.x + s2.y + bdv)));
        outb[lastbase + j] = o;
        if (j == lastcnt - 1) o_last = o;
    }
    // ---- constant tail fill (same-wave visibility; R3-proven pattern) ----
    const float fill = o_last;
    for (int i = t + j; i < 1024; i += 64) outb[i] = fill;
}

extern "C" void kernel_launch(void* const* d_in, const int* in_sizes, int n_in,
                              void* d_out, int out_size, void* d_ws, size_t ws_size,
                              hipStream_t stream) {
    (void)in_sizes; (void)n_in; (void)d_ws; (void)ws_size; (void)out_size;
    const float* x  = (const float*)d_in[0];
    const int*   t  = (const int*)d_in[1];
    const float* W  = (const float*)d_in[2];
    const float* U  = (const float*)d_in[3];
    const float* bb = (const float*)d_in[4];
    const float* Wd = (const float*)d_in[5];
    const float* bd = (const float*)d_in[6];
    float* out = (float*)d_out;

    hipLaunchKernelGGL(gru1_kernel, dim3(512), dim3(64), 0, stream,
                       x, t, W, U, bb, Wd, bd, out);
}